// Round 1
// baseline (321.688 us; speedup 1.0000x reference)
//
#include <hip/hip_runtime.h>

// Problem constants (static per reference): x shape (B, C, H, W) fp32
#define B   64
#define C   2048
#define H   24
#define W   12
#define S   (H * W)        // 288 spatial positions per (b, c)
#define S4  (S / 4)        // 72 float4 per channel slice
#define W4  (W / 4)        // 3 float4 per row
#define NCH 32             // channel chunks
#define CCH (C / NCH)      // 64 channels per chunk
#define RH  8              // round(0.33 * 24)

// Native clang vector type — required by __builtin_nontemporal_store
// (HIP's float4 is a struct wrapper it rejects). Lowers to dwordx4 ops.
typedef float f4 __attribute__((ext_vector_type(4)));

// ---------------------------------------------------------------------------
// Kernel 1: read-only energy pass. Block (chunk, b), 288 threads.
// Thread t, iteration k accesses float4 index t + 288k within the chunk's
// 4608-float4 span -> the block walks contiguous 4.6 KB spans, perfectly
// coalesced. Thread t's 4 spatial positions are fixed -> register accumulate.
// Side effect: x ends up resident in L3 (144 MiB < 256 MiB) for kernel 2.
// ---------------------------------------------------------------------------
__global__ __launch_bounds__(288) void k_energy(const float* __restrict__ x,
                                                float* __restrict__ part) {
    const int chunk = blockIdx.x;   // 0..NCH-1
    const int b     = blockIdx.y;   // 0..B-1
    const int t     = threadIdx.x;  // 0..287
    const int f     = t % S4;
    const int g     = t / S4;

    const f4* __restrict__ x4 =
        (const f4*)x + (size_t)(b * C + chunk * CCH) * S4;

    f4 acc = {0.f, 0.f, 0.f, 0.f};
    #pragma unroll
    for (int k = 0; k < CCH / 4; ++k) {
        f4 v = x4[t + S * k];
        acc += v * v;
    }

    __shared__ f4 sm4[4][S4];   // 4.6 KB
    sm4[g][f] = acc;
    __syncthreads();

    const float* sm = (const float*)sm4;
    // thread t owns spatial position t (t < 288 == S)
    part[((size_t)b * NCH + chunk) * S + t] =
        sm[0 * S + t] + sm[1 * S + t] + sm[2 * S + t] + sm[3 * S + t];
}

// ---------------------------------------------------------------------------
// Kernel 2 (fused select + masked copy). Same (chunk, b) x 288 geometry.
// Each block redundantly reduces the 32 chunk partials of its sample
// (36 KB, L2/L3-resident -> cheap), computes the top-RH row mask in LDS,
// then does the masked copy. Fusing removes the k_select dispatch.
//
// Tie semantics match stable argsort(ascending)[-RH:]: on equal values the
// larger index wins a top (dropped) slot.
//
// Copy: since idx = t + 288k and 288 % 72 == 0, the spatial row
// h = (t%72)/3 is CONSTANT per thread. Branch at loop level: kept lanes do
// load -> nontemporal store (bit-exact copy); dropped lanes store zeros and
// NEVER issue loads (masked-out lanes fetch nothing -> less L3 read traffic).
// x reads mostly hit L3 (kernel 1 warmed it); nontemporal stores keep out
// from evicting x mid-kernel.
// ---------------------------------------------------------------------------
__global__ __launch_bounds__(288) void k_select_copy(const float* __restrict__ x,
                                                     const float* __restrict__ part,
                                                     float* __restrict__ out) {
    const int chunk = blockIdx.x;
    const int b     = blockIdx.y;
    const int t     = threadIdx.x;  // 0..287

    __shared__ float act[S];
    __shared__ float rm[H];
    __shared__ int   keepRow[H];

    // 1. reduce the 32 chunk partials -> act[288] (coalesced across t)
    {
        const float* p = part + (size_t)b * NCH * S + t;
        float sum = 0.f;
        #pragma unroll
        for (int ch = 0; ch < NCH; ch++) sum += p[(size_t)ch * S];
        act[t] = sum;
    }
    __syncthreads();

    // 2. per-row max over width -> rm[24]
    if (t < H) {
        float m = act[t * W];
        #pragma unroll
        for (int w = 1; w < W; w++) m = fmaxf(m, act[t * W + w]);
        rm[t] = m;
    }
    __syncthreads();

    // 3. rank rows; drop the top RH (ties: larger index dropped first)
    if (t < H) {
        const float mt = rm[t];
        int cnt = 0;
        #pragma unroll
        for (int j = 0; j < H; j++) {
            float mj = rm[j];
            if (mj > mt || (mj == mt && j > t)) cnt++;
        }
        keepRow[t] = (cnt < RH) ? 0 : 1;
    }
    __syncthreads();

    // 4. masked copy
    const int h = (t % S4) / W4;
    const size_t base4 = (size_t)(b * C + chunk * CCH) * S4;
    const f4* __restrict__ x4 = (const f4*)x + base4;
    f4* __restrict__       o4 = (f4*)out + base4;

    if (keepRow[h]) {
        #pragma unroll
        for (int k = 0; k < CCH / 4; ++k) {
            f4 v = x4[t + S * k];
            __builtin_nontemporal_store(v, &o4[t + S * k]);
        }
    } else {
        const f4 z = {0.f, 0.f, 0.f, 0.f};
        #pragma unroll
        for (int k = 0; k < CCH / 4; ++k) {
            __builtin_nontemporal_store(z, &o4[t + S * k]);
        }
    }
}

extern "C" void kernel_launch(void* const* d_in, const int* in_sizes, int n_in,
                              void* d_out, int out_size, void* d_ws, size_t ws_size,
                              hipStream_t stream) {
    const float* x   = (const float*)d_in[0];
    float*       out = (float*)d_out;

    // ws layout: [ partials: B*NCH*S floats = 2.36 MB ]
    float* part = (float*)d_ws;

    k_energy<<<dim3(NCH, B), 288, 0, stream>>>(x, part);
    k_select_copy<<<dim3(NCH, B), 288, 0, stream>>>(x, part, out);
}

// Round 2
// 278.026 us; speedup vs baseline: 1.1570x; 1.1570x over previous
//
#include <hip/hip_runtime.h>

// Problem constants (static per reference): x shape (B, C, H, W) fp32
#define B   64
#define C   2048
#define H   24
#define W   12
#define S   (H * W)        // 288 spatial positions per (b, c)
#define S4  (S / 4)        // 72 float4 per channel slice
#define W4  (W / 4)        // 3 float4 per row
#define NCH 32             // channel chunks
#define CCH (C / NCH)      // 64 channels per chunk
#define RH  8              // round(0.33 * 24)

// Native clang vector type — required by __builtin_nontemporal_store
// (HIP's float4 is a struct wrapper it rejects). Lowers to dwordx4 ops.
typedef float f4 __attribute__((ext_vector_type(4)));

// ---------------------------------------------------------------------------
// Kernel 1: read-only energy pass. Block (chunk, b), 288 threads.
// Thread t, iteration k accesses float4 index t + 288k within the chunk's
// 4608-float4 span -> the block walks contiguous 4.6 KB spans, perfectly
// coalesced. Thread t's 4 spatial positions are fixed -> register accumulate.
// Side effect: x ends up resident in L3 (144 MiB < 256 MiB) for kernel 2.
// ---------------------------------------------------------------------------
__global__ __launch_bounds__(288) void k_energy(const float* __restrict__ x,
                                                float* __restrict__ part) {
    const int chunk = blockIdx.x;   // 0..NCH-1
    const int b     = blockIdx.y;   // 0..B-1
    const int t     = threadIdx.x;  // 0..287
    const int f     = t % S4;
    const int g     = t / S4;

    const f4* __restrict__ x4 =
        (const f4*)x + (size_t)(b * C + chunk * CCH) * S4;

    f4 acc = {0.f, 0.f, 0.f, 0.f};
    #pragma unroll
    for (int k = 0; k < CCH / 4; ++k) {
        f4 v = x4[t + S * k];
        acc += v * v;
    }

    __shared__ f4 sm4[4][S4];   // 4.6 KB
    sm4[g][f] = acc;
    __syncthreads();

    const float* sm = (const float*)sm4;
    // thread t owns spatial position t (t < 288 == S)
    part[((size_t)b * NCH + chunk) * S + t] =
        sm[0 * S + t] + sm[1 * S + t] + sm[2 * S + t] + sm[3 * S + t];
}

// ---------------------------------------------------------------------------
// Kernel 2 (fused select + masked copy). Same (chunk, b) x 288 geometry.
// Each block redundantly reduces the 32 chunk partials of its sample
// (36 KB, L2/L3-resident -> ~2.5 us aggregate), computes the top-RH row mask
// in LDS, then does the masked copy. Fusing removes the k_select dispatch.
//
// Tie semantics match stable argsort(ascending)[-RH:]: on equal values the
// larger index wins a top (dropped) slot.
//
// Copy: UNIFORM multiply-mask, no branch. Round-1 lesson: branching on
// keepRow[h] is wave-divergent (h varies across a wave's lanes) -> both
// paths run exec-masked -> partial-wave stores break write-combining
// (~1.8 TB/s write, +24 MB partial-line overshoot). The multiply form keeps
// every store a full-wave contiguous 1 KB transaction. keep is 1.0 or 0.0;
// 0*x == 0 exactly (inputs finite), 1*x is bit-exact.
// Since idx = t + 288k and 288 % 72 == 0, h = (t%72)/3 is constant per
// thread -> one LDS mask read before the loop.
// ---------------------------------------------------------------------------
__global__ __launch_bounds__(288) void k_select_copy(const float* __restrict__ x,
                                                     const float* __restrict__ part,
                                                     float* __restrict__ out) {
    const int chunk = blockIdx.x;
    const int b     = blockIdx.y;
    const int t     = threadIdx.x;  // 0..287

    __shared__ float act[S];
    __shared__ float rm[H];
    __shared__ float keepRow[H];

    // 1. reduce the 32 chunk partials -> act[288] (coalesced across t)
    {
        const float* p = part + (size_t)b * NCH * S + t;
        float sum = 0.f;
        #pragma unroll
        for (int ch = 0; ch < NCH; ch++) sum += p[(size_t)ch * S];
        act[t] = sum;
    }
    __syncthreads();

    // 2. per-row max over width -> rm[24]
    if (t < H) {
        float m = act[t * W];
        #pragma unroll
        for (int w = 1; w < W; w++) m = fmaxf(m, act[t * W + w]);
        rm[t] = m;
    }
    __syncthreads();

    // 3. rank rows; drop the top RH (ties: larger index dropped first)
    if (t < H) {
        const float mt = rm[t];
        int cnt = 0;
        #pragma unroll
        for (int j = 0; j < H; j++) {
            float mj = rm[j];
            if (mj > mt || (mj == mt && j > t)) cnt++;
        }
        keepRow[t] = (cnt < RH) ? 0.0f : 1.0f;
    }
    __syncthreads();

    // 4. masked copy (uniform, full-wave stores)
    const int h = (t % S4) / W4;
    const float keep = keepRow[h];

    const size_t base4 = (size_t)(b * C + chunk * CCH) * S4;
    const f4* __restrict__ x4 = (const f4*)x + base4;
    f4* __restrict__       o4 = (f4*)out + base4;

    #pragma unroll
    for (int k = 0; k < CCH / 4; ++k) {
        f4 v = x4[t + S * k];
        f4 r = v * keep;
        __builtin_nontemporal_store(r, &o4[t + S * k]);
    }
}

extern "C" void kernel_launch(void* const* d_in, const int* in_sizes, int n_in,
                              void* d_out, int out_size, void* d_ws, size_t ws_size,
                              hipStream_t stream) {
    const float* x   = (const float*)d_in[0];
    float*       out = (float*)d_out;

    // ws layout: [ partials: B*NCH*S floats = 2.36 MB ]
    float* part = (float*)d_ws;

    k_energy<<<dim3(NCH, B), 288, 0, stream>>>(x, part);
    k_select_copy<<<dim3(NCH, B), 288, 0, stream>>>(x, part, out);
}

// Round 3
// 276.189 us; speedup vs baseline: 1.1647x; 1.0066x over previous
//
#include <hip/hip_runtime.h>

// Problem constants (static per reference): x shape (B, C, H, W) fp32
#define B   64
#define C   2048
#define H   24
#define W   12
#define S   (H * W)        // 288 spatial positions per (b, c)
#define S4  (S / 4)        // 72 float4 per channel slice
#define W4  (W / 4)        // 3 float4 per row
#define NCH 32             // channel chunks
#define CCH (C / NCH)      // 64 channels per chunk
#define RH  8              // round(0.33 * 24)

// Native clang vector type — required by __builtin_nontemporal_store
// (HIP's float4 is a struct wrapper it rejects). Lowers to dwordx4 ops.
typedef float f4 __attribute__((ext_vector_type(4)));

// ---------------------------------------------------------------------------
// Kernel 1: read-only energy pass. Block (chunk, b), 288 threads.
// Thread t, iteration k accesses float4 index t + 288k within the chunk's
// 4608-float4 span -> the block walks contiguous 4.6 KB spans, perfectly
// coalesced. Thread t's 4 spatial positions are fixed -> register accumulate.
// Loads batched 8-deep explicitly (round-2 theory: compiler was pipelining
// only ~4-deep -> latency-exposed stalls).
// Side effect: x ends up resident in L3 (144 MiB < 256 MiB) for kernel 2.
// ---------------------------------------------------------------------------
__global__ __launch_bounds__(288) void k_energy(const float* __restrict__ x,
                                                float* __restrict__ part) {
    const int chunk = blockIdx.x;   // 0..NCH-1
    const int b     = blockIdx.y;   // 0..B-1
    const int t     = threadIdx.x;  // 0..287
    const int f     = t % S4;
    const int g     = t / S4;

    const f4* __restrict__ x4 =
        (const f4*)x + (size_t)(b * C + chunk * CCH) * S4;

    f4 acc = {0.f, 0.f, 0.f, 0.f};
    #pragma unroll
    for (int kk = 0; kk < 2; ++kk) {
        f4 v[8];
        #pragma unroll
        for (int j = 0; j < 8; ++j) v[j] = x4[t + S * (kk * 8 + j)];
        #pragma unroll
        for (int j = 0; j < 8; ++j) acc += v[j] * v[j];
    }

    __shared__ f4 sm4[4][S4];   // 4.6 KB
    sm4[g][f] = acc;
    __syncthreads();

    const float* sm = (const float*)sm4;
    // thread t owns spatial position t (t < 288 == S)
    part[((size_t)b * NCH + chunk) * S + t] =
        sm[0 * S + t] + sm[1 * S + t] + sm[2 * S + t] + sm[3 * S + t];
}

// ---------------------------------------------------------------------------
// Kernel 2 (fused select + masked copy). Same (chunk, b) x 288 geometry.
//
// Ordering trick: the copy loads do NOT depend on the mask, so the first
// half of the x tile (8 f4/thread) is prefetched BEFORE the mask phase.
// Nearly the whole grid is co-resident (2048 blocks x 288 thr), so without
// this the reduce+select phase (~32 L2 loads + 2 barriers) is pure serial
// prologue on the critical path; with it, the mask phase hides under the
// x-load latency (the reduce's own vmcnt wait drains the earlier x loads
// for free).
//
// Tie semantics match stable argsort(ascending)[-RH:]: on equal values the
// larger index wins a top (dropped) slot.
//
// Copy: UNIFORM multiply-mask, no branch (round-1 lesson: branching on
// keepRow[h] is wave-divergent -> partial-wave stores break write-combining,
// ~1.8 TB/s write + 24 MB partial-line overshoot). keep is 1.0 or 0.0;
// 0*x == 0 exactly (inputs finite), 1*x is bit-exact.
// Since idx = t + 288k and 288 % 72 == 0, h = (t%72)/3 is constant per
// thread -> one LDS mask read before the stores.
// Nontemporal stores keep `out` from evicting x's L3 residency.
// ---------------------------------------------------------------------------
__global__ __launch_bounds__(288) void k_select_copy(const float* __restrict__ x,
                                                     const float* __restrict__ part,
                                                     float* __restrict__ out) {
    const int chunk = blockIdx.x;
    const int b     = blockIdx.y;
    const int t     = threadIdx.x;  // 0..287

    __shared__ float act[S];
    __shared__ float rm[H];
    __shared__ float keepRow[H];

    const size_t base4 = (size_t)(b * C + chunk * CCH) * S4;
    const f4* __restrict__ x4 = (const f4*)x + base4;
    f4* __restrict__       o4 = (f4*)out + base4;

    // 0. prefetch first half of the tile (loads are mask-independent)
    f4 v[8];
    #pragma unroll
    for (int j = 0; j < 8; ++j) v[j] = x4[t + S * j];

    // 1. reduce the 32 chunk partials -> act[288] (coalesced across t)
    {
        const float* p = part + (size_t)b * NCH * S + t;
        float sum = 0.f;
        #pragma unroll
        for (int ch = 0; ch < NCH; ch++) sum += p[(size_t)ch * S];
        act[t] = sum;
    }
    __syncthreads();

    // 2. per-row max over width -> rm[24]
    if (t < H) {
        float m = act[t * W];
        #pragma unroll
        for (int w = 1; w < W; w++) m = fmaxf(m, act[t * W + w]);
        rm[t] = m;
    }
    __syncthreads();

    // 3. rank rows; drop the top RH (ties: larger index dropped first)
    if (t < H) {
        const float mt = rm[t];
        int cnt = 0;
        #pragma unroll
        for (int j = 0; j < H; j++) {
            float mj = rm[j];
            if (mj > mt || (mj == mt && j > t)) cnt++;
        }
        keepRow[t] = (cnt < RH) ? 0.0f : 1.0f;
    }
    __syncthreads();

    // 4. masked copy (uniform, full-wave 16B stores)
    const int h = (t % S4) / W4;
    const float keep = keepRow[h];

    #pragma unroll
    for (int j = 0; j < 8; ++j)
        __builtin_nontemporal_store(v[j] * keep, &o4[t + S * j]);

    // second half: 8-deep batched load then store
    f4 u[8];
    #pragma unroll
    for (int j = 0; j < 8; ++j) u[j] = x4[t + S * (8 + j)];
    #pragma unroll
    for (int j = 0; j < 8; ++j)
        __builtin_nontemporal_store(u[j] * keep, &o4[t + S * (8 + j)]);
}

extern "C" void kernel_launch(void* const* d_in, const int* in_sizes, int n_in,
                              void* d_out, int out_size, void* d_ws, size_t ws_size,
                              hipStream_t stream) {
    const float* x   = (const float*)d_in[0];
    float*       out = (float*)d_out;

    // ws layout: [ partials: B*NCH*S floats = 2.36 MB ]
    float* part = (float*)d_ws;

    k_energy<<<dim3(NCH, B), 288, 0, stream>>>(x, part);
    k_select_copy<<<dim3(NCH, B), 288, 0, stream>>>(x, part, out);
}